// Round 11
// baseline (415.843 us; speedup 1.0000x reference)
//
#include <hip/hip_runtime.h>

// OSQP batched ADMM, B=256 N=128 M=192, 400 iters.
// R16: loop reverted VERBATIM to R10 (best measured 256us; R15's eps-exit
// never fired +10us, reorder neutral). Precompute Phase A de-staged: A read
// directly from global (VMEM pipe, L2-resident: 96KB/block x 32 blocks/XCD
// = 3MB < 4MB L2) instead of 16-way-redundant LDS broadcast reads (576
// ds_read_b128/thread ~ 55k cy) + 12 barriers. Phase C already reads A from
// global and works. Phase B GJ untouched: 64 b128/pivot/CU is a delivery
// floor (every (row,col) needs its pivot element); serial ~400cy/pivot is
// the remaining cost, only an algorithm change beats it.
// Algebra: M = P + sI + rho*AtA (SPD);  Wt = A*Minv;  c = Minv q
//   V = A Minv At;  d = A c
//   iterate (s_0=0), state (p, s, Sacc):
//     r = V s ; w = r - d ; v = a*w + p ; z = med3(v,l,u) ;
//     s' = rho*(2z - v) ; Sacc' = (1-a)Sacc + a*s ; p' = v - a*z
//   epilogue: x = Wt^T Sacc - c

#define Nn 128
#define Mm 192
constexpr float RHO_    = 0.1f;
constexpr float SIGMA_  = 1e-6f;
constexpr float ALPHA_  = 1.6f;
constexpr int   NITERS_ = 400;

typedef float v2f __attribute__((ext_vector_type(2)));
typedef float v4f __attribute__((ext_vector_type(4)));

template<int CTRL>
__device__ __forceinline__ float dpp_add(float x) {
  // old = x so GCNDPPCombine folds to v_add_f32_dpp
  int y = __builtin_amdgcn_update_dpp(__float_as_int(x), __float_as_int(x),
                                      CTRL, 0xF, 0xF, false);
  return x + __int_as_float(y);
}

//======================= Kernel 1: precompute WtT, c ===============================
// [R3-validated GJ core, unchanged]
template<int K0>
__device__ __forceinline__ void gj_block(float rr[32], float* __restrict__ buf0,
                                         float* __restrict__ buf1,
                                         const int irow, const int qq) {
  const bool qsel = (qq == K0);
  #pragma unroll
  for (int kk = 0; kk < 32; kk++) {
    const int k = 32*K0 + kk;
    float* wb = ((kk & 1) == 0) ? buf0 : buf1;
    if (irow == k) {
      #pragma unroll
      for (int j4 = 0; j4 < 8; j4++)
        *(float4*)&wb[36*qq + 4*j4] = *(const float4*)&rr[4*j4];
    }
    __syncthreads();
    const float akk  = wb[36*K0 + kk];
    float pinv = __builtin_amdgcn_rcpf(akk);
    pinv = pinv + pinv*(1.0f - akk*pinv);
    constexpr int QP = K0 | (K0<<2) | (K0<<4) | (K0<<6);
    const int fi = __builtin_amdgcn_update_dpp(__float_as_int(rr[kk]),
                      __float_as_int(rr[kk]), QP, 0xF, 0xF, false);
    const float f = __int_as_float(fi);
    const bool piv = (irow == k);
    float gfac = f * pinv;
    gfac = piv ? (1.0f - pinv) : gfac;
    float rk[32];
    #pragma unroll
    for (int j4 = 0; j4 < 8; j4++)
      *(float4*)&rk[4*j4] = *(const float4*)&wb[36*qq + 4*j4];
    #pragma unroll
    for (int j = 0; j < 32; j++) rr[j] -= gfac * rk[j];
    const float pivfix = piv ? pinv : -gfac;
    if (qsel) rr[kk] = pivfix;
  }
}

__global__ void __launch_bounds__(512, 2)
precompute_kernel(const float* __restrict__ Pg, const float* __restrict__ qg,
                  const float* __restrict__ Ag, float* __restrict__ wsWt,
                  float* __restrict__ wsC)
{
  __shared__ float smem[16384];
  const int t = threadIdx.x;
  const int b = blockIdx.x;
  const float* __restrict__ Pb = Pg + (size_t)b*Nn*Nn;
  const float* __restrict__ qb = qg + (size_t)b*Nn;
  const float* __restrict__ Ab = Ag + (size_t)b*Mm*Nn;

  //---- Phase A: S = P + sigma*I + rho * A^T A  (A direct from global/L2) ----
  {
    const int ar = t & 31;
    const int bc = t >> 5;
    float acc[4][8];
    #pragma unroll
    for (int a=0;a<4;a++)
      #pragma unroll
      for (int j=0;j<8;j++) acc[a][j]=0.f;

    #pragma unroll 2
    for (int m = 0; m < Mm; m++) {
      const float4 ra  = *(const float4*)&Ab[m*Nn + 4*ar];
      const float4 cb0 = *(const float4*)&Ab[m*Nn + 8*bc];
      const float4 cb1 = *(const float4*)&Ab[m*Nn + 8*bc + 4];
      const float rv[4] = {ra.x, ra.y, ra.z, ra.w};
      const float cv[8] = {cb0.x,cb0.y,cb0.z,cb0.w,cb1.x,cb1.y,cb1.z,cb1.w};
      #pragma unroll
      for (int a=0;a<4;a++)
        #pragma unroll
        for (int j=0;j<8;j++) acc[a][j] += rv[a]*cv[j];
    }
    #pragma unroll
    for (int a=0;a<4;a++) {
      const int i = 4*ar + a;
      #pragma unroll
      for (int j=0;j<8;j++) {
        const int jj = 8*bc + j;
        float v = Pb[i*Nn + jj] + RHO_*acc[a][j];
        if (i == jj) v += SIGMA_;
        smem[i*Nn + jj] = v;
      }
    }
    __syncthreads();
  }

  //---- Phase B: Gauss-Jordan inverse ----
  {
    const int irow = t >> 2;
    const int qq   = t & 3;
    float rr[32];
    #pragma unroll
    for (int j=0;j<32;j++) rr[j] = smem[irow*Nn + 32*qq + j];
    __syncthreads();
    float* buf0 = smem;
    float* buf1 = smem + 144;
    gj_block<0>(rr, buf0, buf1, irow, qq);
    gj_block<1>(rr, buf0, buf1, irow, qq);
    gj_block<2>(rr, buf0, buf1, irow, qq);
    gj_block<3>(rr, buf0, buf1, irow, qq);
    __syncthreads();
    #pragma unroll
    for (int j=0;j<32;j++) smem[irow*Nn + 32*qq + j] = rr[j];
  }
  __syncthreads();

  //---- Phase C: WtT[k][j] = (A*Minv)[j][k] -> wsWt (transposed!); c = Minv q ----
  {
    const int jr = t & 63, kc = t >> 6;
    v2f acc[3][8];
    #pragma unroll
    for (int a=0;a<3;a++)
      #pragma unroll
      for (int p=0;p<8;p++) acc[a][p] = (v2f){0.f,0.f};

    for (int mi=0; mi<32; mi++) {
      const v4f a0 = *(const v4f*)&Ab[(jr      )*Nn + 4*mi];
      const v4f a1 = *(const v4f*)&Ab[(jr +  64)*Nn + 4*mi];
      const v4f a2 = *(const v4f*)&Ab[(jr + 128)*Nn + 4*mi];
      const float am[3][4] = {{a0.x,a0.y,a0.z,a0.w},
                              {a1.x,a1.y,a1.z,a1.w},
                              {a2.x,a2.y,a2.z,a2.w}};
      #pragma unroll
      for (int q=0;q<4;q++) {
        const int m = 4*mi + q;
        const v4f w0 = *(const v4f*)&smem[m*Nn + 16*kc +  0];
        const v4f w1 = *(const v4f*)&smem[m*Nn + 16*kc +  4];
        const v4f w2 = *(const v4f*)&smem[m*Nn + 16*kc +  8];
        const v4f w3 = *(const v4f*)&smem[m*Nn + 16*kc + 12];
        const v2f wp[8] = {(v2f){w0.x,w0.y},(v2f){w0.z,w0.w},
                           (v2f){w1.x,w1.y},(v2f){w1.z,w1.w},
                           (v2f){w2.x,w2.y},(v2f){w2.z,w2.w},
                           (v2f){w3.x,w3.y},(v2f){w3.z,w3.w}};
        #pragma unroll
        for (int a=0;a<3;a++) {
          const v2f amv = (v2f){am[a][q], am[a][q]};
          #pragma unroll
          for (int p=0;p<8;p++) acc[a][p] += amv * wp[p];
        }
      }
    }
    // transposed store: WtT[col][j], lanes (jr) run along j -> coalesced
    float* wb = wsWt + (size_t)b*Nn*Mm;
    #pragma unroll
    for (int a=0;a<3;a++) {
      const int j = jr + 64*a;
      #pragma unroll
      for (int p=0;p<8;p++) {
        const int col = 16*kc + 2*p;
        wb[(size_t)(col    )*Mm + j] = acc[a][p].x;
        wb[(size_t)(col + 1)*Mm + j] = acc[a][p].y;
      }
    }
  }
  if (t < Nn) {
    float cc = 0.f;
    #pragma unroll 4
    for (int k=0;k<Nn;k++) cc += smem[k*Nn + t] * qb[k];
    wsC[(size_t)b*Nn + t] = cc;
  }
}

//======================= Kernel 2: row-sharing V-space ADMM loop [R10 verbatim] ====
#define WT_LD 196                       // padded WT row stride (floats)
#define S_SLOT 36                       // padded slot per 24-float s-chunk (bank-spread)
#define S_BUF  (8*S_SLOT)               // 288 floats per s buffer
#define OFF_S0   (Nn*WT_LD)             // 25088
#define OFF_S1   (OFF_S0 + S_BUF)       // 25376
#define OFF_SACC (OFF_S1 + S_BUF)       // 25664
#define OFF_C    (OFF_SACC + Mm)        // 25856
#define OFF_FLAG (OFF_C + Nn)           // 25984
#define LOOP_LDS_FLOATS (OFF_FLAG + 2)  // 25986 floats = 103944 B

__global__ __launch_bounds__(512, 2) void
loop_kernel(const float* __restrict__ Ag, const float* __restrict__ lg,
            const float* __restrict__ ug, const float* __restrict__ wsWtT,
            const float* __restrict__ wsC, float* __restrict__ outg)
{
  extern __shared__ float smem[];
  const int t = threadIdx.x, b = blockIdx.x;
  // eighth e on lane bits {0,1,3}; row-slot rw on bits {2,4,5}; wave = t>>6
  const int e  = (t & 3) | ((t >> 1) & 4);            // 0..7
  const int rw = ((t >> 2) & 1) | ((t >> 3) & 6);     // 0..7
  const int j0 = ((t >> 6) << 3) | rw;                // 0..63; rows j0,+64,+128
  const float* __restrict__ Wg = wsWtT + (size_t)b*Nn*Mm;   // [128][192]
  const float* __restrict__ cb = wsC  + (size_t)b*Nn;
  const float* __restrict__ Ab = Ag   + (size_t)b*Mm*Nn;

  float* WT    = smem;                 // [128][196]
  float* sT0   = smem + OFF_S0;        // padded: row j at 36*(j/24) + j%24
  float* sT1   = smem + OFF_S1;
  float* sacc  = smem + OFF_SACC;      // plain [192]
  float* c_s   = smem + OFF_C;
  float* sflag = smem + OFF_FLAG;

  // ---- stage WtT into LDS: wave w covers rows k=kb*8+w, 64-float col segments
  for (int kb = 0; kb < 16; kb++) {
    const int k  = (kb << 3) | (t >> 6);
    const int jc = t & 63;
    WT[k*WT_LD + jc]       = Wg[(size_t)k*Mm + jc];
    WT[k*WT_LD + 64 + jc]  = Wg[(size_t)k*Mm + 64 + jc];
    WT[k*WT_LD + 128 + jc] = Wg[(size_t)k*Mm + 128 + jc];
  }
  if (t < Nn) c_s[t] = cb[t];
  if (t < S_BUF) sT0[t] = 0.f;
  if (t < 2) sflag[t] = 0.f;
  __syncthreads();

  // ---- per-lane row pointers, bounds ----
  const float* A0 = Ab + (size_t)j0*Nn;
  const float* A1 = A0 + (size_t)64*Nn;
  const float* A2 = A0 + (size_t)128*Nn;
  float lreg[3], ureg[3];
  lreg[0] = lg[(size_t)b*Mm + j0];       ureg[0] = ug[(size_t)b*Mm + j0];
  lreg[1] = lg[(size_t)b*Mm + j0 + 64];  ureg[1] = ug[(size_t)b*Mm + j0 + 64];
  lreg[2] = lg[(size_t)b*Mm + j0 + 128]; ureg[2] = ug[(size_t)b*Mm + j0 + 128];

  // ---- d = A_j . c  (eighth partial over k in [16e,16e+16), dpp-combined) ----
  float dr[3];
  {
    const float4* cr = (const float4*)(c_s + 16*e);
    const float4 c0 = cr[0], c1 = cr[1], c2 = cr[2], c3 = cr[3];
    const float* Aj[3] = {A0, A1, A2};
    #pragma unroll
    for (int a = 0; a < 3; a++) {
      const float4* ar = (const float4*)(Aj[a] + 16*e);
      const float4 a0 = ar[0], a1 = ar[1], a2 = ar[2], a3 = ar[3];
      float dp = a0.x*c0.x + a0.y*c0.y + a0.z*c0.z + a0.w*c0.w
               + a1.x*c1.x + a1.y*c1.y + a1.z*c1.z + a1.w*c1.w
               + a2.x*c2.x + a2.y*c2.y + a2.z*c2.z + a2.w*c2.w
               + a3.x*c3.x + a3.y*c3.y + a3.z*c3.z + a3.w*c3.w;
      dp = dpp_add<0xB1>(dp);    // xor-1 (quad)
      dp = dpp_add<0x4E>(dp);    // xor-2 (quad)
      dp = dpp_add<0x128>(dp);   // xor-8 (row_ror:8)
      dr[a] = dp;
    }
  }

  // ---- V eighth for 3 rows: Ve[a][p] = V[j0+64a][24e+2p .. +2) ----
  v2f Ve[3][12];
  #pragma unroll
  for (int a = 0; a < 3; a++)
    #pragma unroll
    for (int p = 0; p < 12; p++) Ve[a][p] = (v2f){0.f, 0.f};
  for (int k4 = 0; k4 < 32; k4++) {
    const v4f a4_0 = *(const v4f*)&A0[4*k4];
    const v4f a4_1 = *(const v4f*)&A1[4*k4];
    const v4f a4_2 = *(const v4f*)&A2[4*k4];
    #pragma unroll
    for (int kk = 0; kk < 4; kk++) {
      const float* wp = &WT[(4*k4 + kk)*WT_LD + 24*e];
      const v4f w0 = *(const v4f*)&wp[0];
      const v4f w1 = *(const v4f*)&wp[4];
      const v4f w2 = *(const v4f*)&wp[8];
      const v4f w3 = *(const v4f*)&wp[12];
      const v4f w4 = *(const v4f*)&wp[16];
      const v4f w5 = *(const v4f*)&wp[20];
      const v2f wv[12] = {(v2f){w0.x,w0.y},(v2f){w0.z,w0.w},
                          (v2f){w1.x,w1.y},(v2f){w1.z,w1.w},
                          (v2f){w2.x,w2.y},(v2f){w2.z,w2.w},
                          (v2f){w3.x,w3.y},(v2f){w3.z,w3.w},
                          (v2f){w4.x,w4.y},(v2f){w4.z,w4.w},
                          (v2f){w5.x,w5.y},(v2f){w5.z,w5.w}};
      const float ax0 = a4_0[kk], ax1 = a4_1[kk], ax2 = a4_2[kk];
      const v2f av0 = (v2f){ax0, ax0};
      const v2f av1 = (v2f){ax1, ax1};
      const v2f av2 = (v2f){ax2, ax2};
      #pragma unroll
      for (int p = 0; p < 12; p++) {
        Ve[0][p] = __builtin_elementwise_fma(av0, wv[p], Ve[0][p]);
        Ve[1][p] = __builtin_elementwise_fma(av1, wv[p], Ve[1][p]);
        Ve[2][p] = __builtin_elementwise_fma(av2, wv[p], Ve[2][p]);
      }
    }
  }

  // ---- iteration state ----
  float sreg[3] = {0.f, 0.f, 0.f};
  float preg[3] = {0.f, 0.f, 0.f};
  float Sacc[3] = {0.f, 0.f, 0.f};
  bool cvg = false;
  const int jsel = j0 + 64*((e < 3) ? e : 0);     // writer row (lane e<3)
  const int wsel = S_SLOT*(jsel/24) + (jsel%24);
  const bool wr_act = (e < 3);
  const float* rbase0 = sT0 + S_SLOT*e;
  const float* rbase1 = sT1 + S_SLOT*e;

#define ITER(RP, WR, CHK, PH)                                                  \
  {                                                                            \
    const v4f s0 = *(const v4f*)&(RP)[0];                                      \
    const v4f s1 = *(const v4f*)&(RP)[4];                                      \
    const v4f s2 = *(const v4f*)&(RP)[8];                                      \
    const v4f s3 = *(const v4f*)&(RP)[12];                                     \
    const v4f s4 = *(const v4f*)&(RP)[16];                                     \
    const v4f s5 = *(const v4f*)&(RP)[20];                                     \
    const v2f sv[12] = {(v2f){s0.x,s0.y},(v2f){s0.z,s0.w},                     \
                        (v2f){s1.x,s1.y},(v2f){s1.z,s1.w},                     \
                        (v2f){s2.x,s2.y},(v2f){s2.z,s2.w},                     \
                        (v2f){s3.x,s3.y},(v2f){s3.z,s3.w},                     \
                        (v2f){s4.x,s4.y},(v2f){s4.z,s4.w},                     \
                        (v2f){s5.x,s5.y},(v2f){s5.z,s5.w}};                    \
    float sn[3], pn[3];                                                        \
    _Pragma("unroll")                                                          \
    for (int a = 0; a < 3; a++) {                                              \
      v2f x0 = Ve[a][0] * sv[0];                                               \
      v2f x1 = Ve[a][1] * sv[1];                                               \
      v2f x2 = Ve[a][2] * sv[2];                                               \
      v2f x3 = Ve[a][3] * sv[3];                                               \
      x0 = __builtin_elementwise_fma(Ve[a][4], sv[4], x0);                     \
      x1 = __builtin_elementwise_fma(Ve[a][5], sv[5], x1);                     \
      x2 = __builtin_elementwise_fma(Ve[a][6], sv[6], x2);                     \
      x3 = __builtin_elementwise_fma(Ve[a][7], sv[7], x3);                     \
      x0 = __builtin_elementwise_fma(Ve[a][8], sv[8], x0);                     \
      x1 = __builtin_elementwise_fma(Ve[a][9], sv[9], x1);                     \
      x2 = __builtin_elementwise_fma(Ve[a][10], sv[10], x2);                   \
      x3 = __builtin_elementwise_fma(Ve[a][11], sv[11], x3);                   \
      x0 += x1; x2 += x3; x0 += x2;                                            \
      float pr = x0.x + x0.y;                                                  \
      pr = dpp_add<0xB1>(pr);                                                  \
      pr = dpp_add<0x4E>(pr);                                                  \
      pr = dpp_add<0x128>(pr);                                                 \
      const float w_ = pr - dr[a];                                             \
      const float v_ = fmaf(ALPHA_, w_, preg[a]);                              \
      const float z_ = __builtin_amdgcn_fmed3f(v_, lreg[a], ureg[a]);          \
      sn[a] = RHO_ * fmaf(2.0f, z_, -v_);                                      \
      pn[a] = fmaf(-ALPHA_, z_, v_);                                           \
    }                                                                          \
    const float vsel = (e == 1) ? sn[1] : ((e == 2) ? sn[2] : sn[0]);          \
    if (wr_act) (WR)[wsel] = vsel;                                             \
    if (CHK) {                                                                 \
      if (!(sn[0]==sreg[0] && pn[0]==preg[0] &&                                \
            sn[1]==sreg[1] && pn[1]==preg[1] &&                                \
            sn[2]==sreg[2] && pn[2]==preg[2])) sflag[PH] = 1.f;                \
    }                                                                          \
    _Pragma("unroll")                                                          \
    for (int a = 0; a < 3; a++) {                                              \
      Sacc[a] = fmaf(1.0f - ALPHA_, Sacc[a], ALPHA_ * sreg[a]);                \
      sreg[a] = sn[a]; preg[a] = pn[a];                                        \
    }                                                                          \
    if ((CHK) && t == 0) sflag[(PH) ^ 1] = 0.f;                                \
    __syncthreads();                                                           \
    if (CHK) cvg = (sflag[PH] == 0.f);                                         \
  }

  #pragma unroll 1
  for (int it2 = 0; it2 < NITERS_/2; it2++) {
    ITER(rbase0, sT1, false, 0)
    const bool chk = ((it2 & 3) == 3) && (it2 < NITERS_/2 - 40);
    const int ph = (it2 >> 2) & 1;
    ITER(rbase1, sT0, chk, ph)
    if (cvg) break;   // bitwise fixed point: remaining iterations are identities
  }
#undef ITER
  if (cvg) {
    #pragma unroll
    for (int a = 0; a < 3; a++) Sacc[a] = sreg[a];  // Sacc -> s*; |(-0.6)^80|~2e-18
  }

  // ---- epilogue: x = Wt^T Sacc - c  (= WtT rows . Sacc) ----
  if (wr_act) {
    const float ssel = (e == 1) ? Sacc[1] : ((e == 2) ? Sacc[2] : Sacc[0]);
    sacc[jsel] = ssel;
  }
  __syncthreads();
  if (t < Nn) {
    const float* wr = &WT[t*WT_LD];
    v2f xa = (v2f){0.f,0.f}, xb = (v2f){0.f,0.f};
    #pragma unroll
    for (int j4 = 0; j4 < 48; j4++) {
      const v4f wv = *(const v4f*)&wr[4*j4];
      const v4f sv = *(const v4f*)&sacc[4*j4];
      xa = __builtin_elementwise_fma((v2f){wv.x,wv.y}, (v2f){sv.x,sv.y}, xa);
      xb = __builtin_elementwise_fma((v2f){wv.z,wv.w}, (v2f){sv.z,sv.w}, xb);
    }
    xa += xb;
    outg[(size_t)b*Nn + t] = xa.x + xa.y - c_s[t];
  }
}

extern "C" void kernel_launch(void* const* d_in, const int* in_sizes, int n_in,
                              void* d_out, int out_size, void* d_ws, size_t ws_size,
                              hipStream_t stream) {
  const float* P = (const float*)d_in[0];
  const float* q = (const float*)d_in[1];
  const float* A = (const float*)d_in[2];
  const float* l = (const float*)d_in[3];
  const float* u = (const float*)d_in[4];
  (void)in_sizes; (void)n_in; (void)out_size; (void)ws_size;
  float* wsWt = (float*)d_ws;                      // WtT: 256*128*192 floats = 25.2 MB
  float* wsC  = wsWt + (size_t)256*Mm*Nn;          // 256*128 floats
  precompute_kernel<<<256, 512, 0, stream>>>(P, q, A, wsWt, wsC);
  loop_kernel<<<256, 512, LOOP_LDS_FLOATS*4, stream>>>(A, l, u, wsWt, wsC, (float*)d_out);
}

// Round 13
// 402.021 us; speedup vs baseline: 1.0344x; 1.0344x over previous
//
#include <hip/hip_runtime.h>

// OSQP batched ADMM, B=256 N=128 M=192, 400 iters.
// R18 == R17 resubmitted verbatim (R17 bench failed on container
// acquisition; kernel never executed). R17 == R10 EXACT RESTORE (best
// measured: 404.05us total, loop 256us, VGPR 72). R11-R16 established:
// every deviation regresses. R16 additionally showed rule-#19 (co-compiled
// kernel perturbation): changing precompute shifted loop_kernel regalloc
// 72->80 VGPR (+4us). This source is the Round-5 kernel verbatim to restore
// the exact codegen context.
// R10: row-sharing. R8 was LDS-instruction-bound (144 broadcast ds_read_b128
// /CU/iter ~1200cy; VALU idle). R9's DPP gather regressed (wrong trade: 36
// VALU movs to save 9 LDS instrs). R10 amortizes each s-read across THREE
// V-rows: 512 thr (8 waves, 2/SIMD), lane owns rows (j0, j0+64, j0+128) at
// s-cols [24e,24e+24), Ve[3][12 v2f]=72 VGPR (fits, no spill). Per iter:
// 6 ds_read_b128 + 36 pk_fma + 9 dpp_add (xor1/xor2 quad + xor8 row_ror:8,
// pure VALU reduce replaces ds_bpermute shfl) + 1 combined masked write
// (lane e<3 writes row j0+64e). LDS instr 168 -> 56 per CU-iter. s-buffers
// padded to 36-float slots so the 8 chunk-lines cover all 32 banks: 0 conflict.
// Algebra: M = P + sI + rho*AtA (SPD);  Wt = A*Minv;  c = Minv q
//   V = A Minv At;  d = A c
//   iterate (s_0=0), state (p = (1-a)z + y/rho, s, Sacc):
//     r = V s ; w = r - d ; v = a*w + p ; z = med3(v,l,u) ;
//     s' = rho*(2z - v) ; Sacc' = (1-a)Sacc + a*s ; p' = v - a*z
//   epilogue: x = Wt^T Sacc - c

#define Nn 128
#define Mm 192
constexpr float RHO_    = 0.1f;
constexpr float SIGMA_  = 1e-6f;
constexpr float ALPHA_  = 1.6f;
constexpr int   NITERS_ = 400;

typedef float v2f __attribute__((ext_vector_type(2)));
typedef float v4f __attribute__((ext_vector_type(4)));

template<int CTRL>
__device__ __forceinline__ float dpp_add(float x) {
  // old = x so GCNDPPCombine folds to v_add_f32_dpp
  int y = __builtin_amdgcn_update_dpp(__float_as_int(x), __float_as_int(x),
                                      CTRL, 0xF, 0xF, false);
  return x + __int_as_float(y);
}

//======================= Kernel 1: precompute WtT, c ===============================
// [R3-validated GJ core, unchanged]
template<int K0>
__device__ __forceinline__ void gj_block(float rr[32], float* __restrict__ buf0,
                                         float* __restrict__ buf1,
                                         const int irow, const int qq) {
  const bool qsel = (qq == K0);
  #pragma unroll
  for (int kk = 0; kk < 32; kk++) {
    const int k = 32*K0 + kk;
    float* wb = ((kk & 1) == 0) ? buf0 : buf1;
    if (irow == k) {
      #pragma unroll
      for (int j4 = 0; j4 < 8; j4++)
        *(float4*)&wb[36*qq + 4*j4] = *(const float4*)&rr[4*j4];
    }
    __syncthreads();
    const float akk  = wb[36*K0 + kk];
    float pinv = __builtin_amdgcn_rcpf(akk);
    pinv = pinv + pinv*(1.0f - akk*pinv);
    constexpr int QP = K0 | (K0<<2) | (K0<<4) | (K0<<6);
    const int fi = __builtin_amdgcn_update_dpp(__float_as_int(rr[kk]),
                      __float_as_int(rr[kk]), QP, 0xF, 0xF, false);
    const float f = __int_as_float(fi);
    const bool piv = (irow == k);
    float gfac = f * pinv;
    gfac = piv ? (1.0f - pinv) : gfac;
    float rk[32];
    #pragma unroll
    for (int j4 = 0; j4 < 8; j4++)
      *(float4*)&rk[4*j4] = *(const float4*)&wb[36*qq + 4*j4];
    #pragma unroll
    for (int j = 0; j < 32; j++) rr[j] -= gfac * rk[j];
    const float pivfix = piv ? pinv : -gfac;
    if (qsel) rr[kk] = pivfix;
  }
}

__global__ void __launch_bounds__(512, 2)
precompute_kernel(const float* __restrict__ Pg, const float* __restrict__ qg,
                  const float* __restrict__ Ag, float* __restrict__ wsWt,
                  float* __restrict__ wsC)
{
  __shared__ float smem[16384];
  const int t = threadIdx.x;
  const int b = blockIdx.x;
  const float* __restrict__ Pb = Pg + (size_t)b*Nn*Nn;
  const float* __restrict__ qb = qg + (size_t)b*Nn;
  const float* __restrict__ Ab = Ag + (size_t)b*Mm*Nn;

  //---- Phase A: S = P + sigma*I + rho * A^T A ----
  {
    const int ar = t & 31;
    const int bc = t >> 5;
    float acc[4][8];
    #pragma unroll
    for (int a=0;a<4;a++)
      #pragma unroll
      for (int j=0;j<8;j++) acc[a][j]=0.f;

    for (int c=0;c<6;c++) {
      __syncthreads();
      {
        const float4* src = (const float4*)(Ab + c*32*Nn);
        float4* dst = (float4*)smem;
        dst[t]     = src[t];
        dst[t+512] = src[t+512];
      }
      __syncthreads();
      #pragma unroll 2
      for (int m=0;m<32;m++) {
        const float4 ra  = *(const float4*)&smem[m*Nn + 4*ar];
        const float4 cb0 = *(const float4*)&smem[m*Nn + 8*bc];
        const float4 cb1 = *(const float4*)&smem[m*Nn + 8*bc + 4];
        const float rv[4] = {ra.x, ra.y, ra.z, ra.w};
        const float cv[8] = {cb0.x,cb0.y,cb0.z,cb0.w,cb1.x,cb1.y,cb1.z,cb1.w};
        #pragma unroll
        for (int a=0;a<4;a++)
          #pragma unroll
          for (int j=0;j<8;j++) acc[a][j] += rv[a]*cv[j];
      }
    }
    __syncthreads();
    #pragma unroll
    for (int a=0;a<4;a++) {
      const int i = 4*ar + a;
      #pragma unroll
      for (int j=0;j<8;j++) {
        const int jj = 8*bc + j;
        float v = Pb[i*Nn + jj] + RHO_*acc[a][j];
        if (i == jj) v += SIGMA_;
        smem[i*Nn + jj] = v;
      }
    }
    __syncthreads();
  }

  //---- Phase B: Gauss-Jordan inverse ----
  {
    const int irow = t >> 2;
    const int qq   = t & 3;
    float rr[32];
    #pragma unroll
    for (int j=0;j<32;j++) rr[j] = smem[irow*Nn + 32*qq + j];
    __syncthreads();
    float* buf0 = smem;
    float* buf1 = smem + 144;
    gj_block<0>(rr, buf0, buf1, irow, qq);
    gj_block<1>(rr, buf0, buf1, irow, qq);
    gj_block<2>(rr, buf0, buf1, irow, qq);
    gj_block<3>(rr, buf0, buf1, irow, qq);
    __syncthreads();
    #pragma unroll
    for (int j=0;j<32;j++) smem[irow*Nn + 32*qq + j] = rr[j];
  }
  __syncthreads();

  //---- Phase C: WtT[k][j] = (A*Minv)[j][k] -> wsWt (transposed!); c = Minv q ----
  {
    const int jr = t & 63, kc = t >> 6;
    v2f acc[3][8];
    #pragma unroll
    for (int a=0;a<3;a++)
      #pragma unroll
      for (int p=0;p<8;p++) acc[a][p] = (v2f){0.f,0.f};

    for (int mi=0; mi<32; mi++) {
      const v4f a0 = *(const v4f*)&Ab[(jr      )*Nn + 4*mi];
      const v4f a1 = *(const v4f*)&Ab[(jr +  64)*Nn + 4*mi];
      const v4f a2 = *(const v4f*)&Ab[(jr + 128)*Nn + 4*mi];
      const float am[3][4] = {{a0.x,a0.y,a0.z,a0.w},
                              {a1.x,a1.y,a1.z,a1.w},
                              {a2.x,a2.y,a2.z,a2.w}};
      #pragma unroll
      for (int q=0;q<4;q++) {
        const int m = 4*mi + q;
        const v4f w0 = *(const v4f*)&smem[m*Nn + 16*kc +  0];
        const v4f w1 = *(const v4f*)&smem[m*Nn + 16*kc +  4];
        const v4f w2 = *(const v4f*)&smem[m*Nn + 16*kc +  8];
        const v4f w3 = *(const v4f*)&smem[m*Nn + 16*kc + 12];
        const v2f wp[8] = {(v2f){w0.x,w0.y},(v2f){w0.z,w0.w},
                           (v2f){w1.x,w1.y},(v2f){w1.z,w1.w},
                           (v2f){w2.x,w2.y},(v2f){w2.z,w2.w},
                           (v2f){w3.x,w3.y},(v2f){w3.z,w3.w}};
        #pragma unroll
        for (int a=0;a<3;a++) {
          const v2f amv = (v2f){am[a][q], am[a][q]};
          #pragma unroll
          for (int p=0;p<8;p++) acc[a][p] += amv * wp[p];
        }
      }
    }
    // transposed store: WtT[col][j], lanes (jr) run along j -> coalesced
    float* wb = wsWt + (size_t)b*Nn*Mm;
    #pragma unroll
    for (int a=0;a<3;a++) {
      const int j = jr + 64*a;
      #pragma unroll
      for (int p=0;p<8;p++) {
        const int col = 16*kc + 2*p;
        wb[(size_t)(col    )*Mm + j] = acc[a][p].x;
        wb[(size_t)(col + 1)*Mm + j] = acc[a][p].y;
      }
    }
  }
  if (t < Nn) {
    float cc = 0.f;
    #pragma unroll 4
    for (int k=0;k<Nn;k++) cc += smem[k*Nn + t] * qb[k];
    wsC[(size_t)b*Nn + t] = cc;
  }
}

//======================= Kernel 2: row-sharing V-space ADMM loop ===================
#define WT_LD 196                       // padded WT row stride (floats)
#define S_SLOT 36                       // padded slot per 24-float s-chunk (bank-spread)
#define S_BUF  (8*S_SLOT)               // 288 floats per s buffer
#define OFF_S0   (Nn*WT_LD)             // 25088
#define OFF_S1   (OFF_S0 + S_BUF)       // 25376
#define OFF_SACC (OFF_S1 + S_BUF)       // 25664
#define OFF_C    (OFF_SACC + Mm)        // 25856
#define OFF_FLAG (OFF_C + Nn)           // 25984
#define LOOP_LDS_FLOATS (OFF_FLAG + 2)  // 25986 floats = 103944 B

__global__ __launch_bounds__(512, 2) void
loop_kernel(const float* __restrict__ Ag, const float* __restrict__ lg,
            const float* __restrict__ ug, const float* __restrict__ wsWtT,
            const float* __restrict__ wsC, float* __restrict__ outg)
{
  extern __shared__ float smem[];
  const int t = threadIdx.x, b = blockIdx.x;
  // eighth e on lane bits {0,1,3}; row-slot rw on bits {2,4,5}; wave = t>>6
  const int e  = (t & 3) | ((t >> 1) & 4);            // 0..7
  const int rw = ((t >> 2) & 1) | ((t >> 3) & 6);     // 0..7
  const int j0 = ((t >> 6) << 3) | rw;                // 0..63; rows j0,+64,+128
  const float* __restrict__ Wg = wsWtT + (size_t)b*Nn*Mm;   // [128][192]
  const float* __restrict__ cb = wsC  + (size_t)b*Nn;
  const float* __restrict__ Ab = Ag   + (size_t)b*Mm*Nn;

  float* WT    = smem;                 // [128][196]
  float* sT0   = smem + OFF_S0;        // padded: row j at 36*(j/24) + j%24
  float* sT1   = smem + OFF_S1;
  float* sacc  = smem + OFF_SACC;      // plain [192]
  float* c_s   = smem + OFF_C;
  float* sflag = smem + OFF_FLAG;

  // ---- stage WtT into LDS: wave w covers rows k=kb*8+w, 64-float col segments
  for (int kb = 0; kb < 16; kb++) {
    const int k  = (kb << 3) | (t >> 6);
    const int jc = t & 63;
    WT[k*WT_LD + jc]       = Wg[(size_t)k*Mm + jc];
    WT[k*WT_LD + 64 + jc]  = Wg[(size_t)k*Mm + 64 + jc];
    WT[k*WT_LD + 128 + jc] = Wg[(size_t)k*Mm + 128 + jc];
  }
  if (t < Nn) c_s[t] = cb[t];
  if (t < S_BUF) sT0[t] = 0.f;
  if (t < 2) sflag[t] = 0.f;
  __syncthreads();

  // ---- per-lane row pointers, bounds ----
  const float* A0 = Ab + (size_t)j0*Nn;
  const float* A1 = A0 + (size_t)64*Nn;
  const float* A2 = A0 + (size_t)128*Nn;
  float lreg[3], ureg[3];
  lreg[0] = lg[(size_t)b*Mm + j0];       ureg[0] = ug[(size_t)b*Mm + j0];
  lreg[1] = lg[(size_t)b*Mm + j0 + 64];  ureg[1] = ug[(size_t)b*Mm + j0 + 64];
  lreg[2] = lg[(size_t)b*Mm + j0 + 128]; ureg[2] = ug[(size_t)b*Mm + j0 + 128];

  // ---- d = A_j . c  (eighth partial over k in [16e,16e+16), dpp-combined) ----
  float dr[3];
  {
    const float4* cr = (const float4*)(c_s + 16*e);
    const float4 c0 = cr[0], c1 = cr[1], c2 = cr[2], c3 = cr[3];
    const float* Aj[3] = {A0, A1, A2};
    #pragma unroll
    for (int a = 0; a < 3; a++) {
      const float4* ar = (const float4*)(Aj[a] + 16*e);
      const float4 a0 = ar[0], a1 = ar[1], a2 = ar[2], a3 = ar[3];
      float dp = a0.x*c0.x + a0.y*c0.y + a0.z*c0.z + a0.w*c0.w
               + a1.x*c1.x + a1.y*c1.y + a1.z*c1.z + a1.w*c1.w
               + a2.x*c2.x + a2.y*c2.y + a2.z*c2.z + a2.w*c2.w
               + a3.x*c3.x + a3.y*c3.y + a3.z*c3.z + a3.w*c3.w;
      dp = dpp_add<0xB1>(dp);    // xor-1 (quad)
      dp = dpp_add<0x4E>(dp);    // xor-2 (quad)
      dp = dpp_add<0x128>(dp);   // xor-8 (row_ror:8)
      dr[a] = dp;
    }
  }

  // ---- V eighth for 3 rows: Ve[a][p] = V[j0+64a][24e+2p .. +2) ----
  v2f Ve[3][12];
  #pragma unroll
  for (int a = 0; a < 3; a++)
    #pragma unroll
    for (int p = 0; p < 12; p++) Ve[a][p] = (v2f){0.f, 0.f};
  for (int k4 = 0; k4 < 32; k4++) {
    const v4f a4_0 = *(const v4f*)&A0[4*k4];
    const v4f a4_1 = *(const v4f*)&A1[4*k4];
    const v4f a4_2 = *(const v4f*)&A2[4*k4];
    #pragma unroll
    for (int kk = 0; kk < 4; kk++) {
      const float* wp = &WT[(4*k4 + kk)*WT_LD + 24*e];
      const v4f w0 = *(const v4f*)&wp[0];
      const v4f w1 = *(const v4f*)&wp[4];
      const v4f w2 = *(const v4f*)&wp[8];
      const v4f w3 = *(const v4f*)&wp[12];
      const v4f w4 = *(const v4f*)&wp[16];
      const v4f w5 = *(const v4f*)&wp[20];
      const v2f wv[12] = {(v2f){w0.x,w0.y},(v2f){w0.z,w0.w},
                          (v2f){w1.x,w1.y},(v2f){w1.z,w1.w},
                          (v2f){w2.x,w2.y},(v2f){w2.z,w2.w},
                          (v2f){w3.x,w3.y},(v2f){w3.z,w3.w},
                          (v2f){w4.x,w4.y},(v2f){w4.z,w4.w},
                          (v2f){w5.x,w5.y},(v2f){w5.z,w5.w}};
      const float ax0 = a4_0[kk], ax1 = a4_1[kk], ax2 = a4_2[kk];
      const v2f av0 = (v2f){ax0, ax0};
      const v2f av1 = (v2f){ax1, ax1};
      const v2f av2 = (v2f){ax2, ax2};
      #pragma unroll
      for (int p = 0; p < 12; p++) {
        Ve[0][p] = __builtin_elementwise_fma(av0, wv[p], Ve[0][p]);
        Ve[1][p] = __builtin_elementwise_fma(av1, wv[p], Ve[1][p]);
        Ve[2][p] = __builtin_elementwise_fma(av2, wv[p], Ve[2][p]);
      }
    }
  }

  // ---- iteration state ----
  float sreg[3] = {0.f, 0.f, 0.f};
  float preg[3] = {0.f, 0.f, 0.f};
  float Sacc[3] = {0.f, 0.f, 0.f};
  bool cvg = false;
  // write slot for this lane (lane e<3 writes row j0+64e); padded address
  const int jsel = j0 + 64*((e < 3) ? e : 0);
  const int wsel = S_SLOT*(jsel/24) + (jsel%24);
  const bool wr_act = (e < 3);
  const float* rbase0 = sT0 + S_SLOT*e;
  const float* rbase1 = sT1 + S_SLOT*e;

#define ITER(RP, WR, CHK, PH)                                                  \
  {                                                                            \
    const v4f s0 = *(const v4f*)&(RP)[0];                                      \
    const v4f s1 = *(const v4f*)&(RP)[4];                                      \
    const v4f s2 = *(const v4f*)&(RP)[8];                                      \
    const v4f s3 = *(const v4f*)&(RP)[12];                                     \
    const v4f s4 = *(const v4f*)&(RP)[16];                                     \
    const v4f s5 = *(const v4f*)&(RP)[20];                                     \
    const v2f sv[12] = {(v2f){s0.x,s0.y},(v2f){s0.z,s0.w},                     \
                        (v2f){s1.x,s1.y},(v2f){s1.z,s1.w},                     \
                        (v2f){s2.x,s2.y},(v2f){s2.z,s2.w},                     \
                        (v2f){s3.x,s3.y},(v2f){s3.z,s3.w},                     \
                        (v2f){s4.x,s4.y},(v2f){s4.z,s4.w},                     \
                        (v2f){s5.x,s5.y},(v2f){s5.z,s5.w}};                    \
    v2f x0[3], x1[3];                                                          \
    _Pragma("unroll")                                                          \
    for (int a = 0; a < 3; a++) { x0[a]=(v2f){0.f,0.f}; x1[a]=(v2f){0.f,0.f}; }\
    _Pragma("unroll")                                                          \
    for (int p = 0; p < 6; p++) {                                              \
      _Pragma("unroll")                                                        \
      for (int a = 0; a < 3; a++) {                                            \
        x0[a] = __builtin_elementwise_fma(Ve[a][2*p],   sv[2*p],   x0[a]);     \
        x1[a] = __builtin_elementwise_fma(Ve[a][2*p+1], sv[2*p+1], x1[a]);     \
      }                                                                        \
    }                                                                          \
    float sn[3], pn[3];                                                        \
    _Pragma("unroll")                                                          \
    for (int a = 0; a < 3; a++) {                                              \
      const v2f xs = x0[a] + x1[a];                                            \
      float pr = xs.x + xs.y;                                                  \
      pr = dpp_add<0xB1>(pr);                                                  \
      pr = dpp_add<0x4E>(pr);                                                  \
      pr = dpp_add<0x128>(pr);                                                 \
      const float w_ = pr - dr[a];                                             \
      const float v_ = fmaf(ALPHA_, w_, preg[a]);                              \
      const float z_ = __builtin_amdgcn_fmed3f(v_, lreg[a], ureg[a]);          \
      sn[a] = RHO_ * fmaf(2.0f, z_, -v_);                                      \
      pn[a] = fmaf(-ALPHA_, z_, v_);                                           \
    }                                                                          \
    const float vsel = (e == 1) ? sn[1] : ((e == 2) ? sn[2] : sn[0]);          \
    if (wr_act) (WR)[wsel] = vsel;                                             \
    if (CHK) {                                                                 \
      if (!(sn[0]==sreg[0] && pn[0]==preg[0] &&                                \
            sn[1]==sreg[1] && pn[1]==preg[1] &&                                \
            sn[2]==sreg[2] && pn[2]==preg[2])) sflag[PH] = 1.f;                \
    }                                                                          \
    _Pragma("unroll")                                                          \
    for (int a = 0; a < 3; a++) {                                              \
      Sacc[a] = fmaf(1.0f - ALPHA_, Sacc[a], ALPHA_ * sreg[a]);                \
      sreg[a] = sn[a]; preg[a] = pn[a];                                        \
    }                                                                          \
    if ((CHK) && t == 0) sflag[(PH) ^ 1] = 0.f;                                \
    __syncthreads();                                                           \
    if (CHK) cvg = (sflag[PH] == 0.f);                                         \
  }

  #pragma unroll 1
  for (int it2 = 0; it2 < NITERS_/2; it2++) {
    ITER(rbase0, sT1, false, 0)
    const bool chk = ((it2 & 3) == 3) && (it2 < NITERS_/2 - 40);
    const int ph = (it2 >> 2) & 1;
    ITER(rbase1, sT0, chk, ph)
    if (cvg) break;   // bitwise fixed point: remaining iterations are identities
  }
#undef ITER
  if (cvg) {
    #pragma unroll
    for (int a = 0; a < 3; a++) Sacc[a] = sreg[a];  // Sacc -> s* ; |(-0.6)^80|~2e-18
  }

  // ---- epilogue: x = Wt^T Sacc - c  (= WtT rows . Sacc) ----
  if (wr_act) {
    const float ssel = (e == 1) ? Sacc[1] : ((e == 2) ? Sacc[2] : Sacc[0]);
    sacc[jsel] = ssel;
  }
  __syncthreads();
  if (t < Nn) {
    const float* wr = &WT[t*WT_LD];
    v2f xa = (v2f){0.f,0.f}, xb = (v2f){0.f,0.f};
    #pragma unroll
    for (int j4 = 0; j4 < 48; j4++) {
      const v4f wv = *(const v4f*)&wr[4*j4];
      const v4f sv = *(const v4f*)&sacc[4*j4];
      xa = __builtin_elementwise_fma((v2f){wv.x,wv.y}, (v2f){sv.x,sv.y}, xa);
      xb = __builtin_elementwise_fma((v2f){wv.z,wv.w}, (v2f){sv.z,sv.w}, xb);
    }
    xa += xb;
    outg[(size_t)b*Nn + t] = xa.x + xa.y - c_s[t];
  }
}

extern "C" void kernel_launch(void* const* d_in, const int* in_sizes, int n_in,
                              void* d_out, int out_size, void* d_ws, size_t ws_size,
                              hipStream_t stream) {
  const float* P = (const float*)d_in[0];
  const float* q = (const float*)d_in[1];
  const float* A = (const float*)d_in[2];
  const float* l = (const float*)d_in[3];
  const float* u = (const float*)d_in[4];
  (void)in_sizes; (void)n_in; (void)out_size; (void)ws_size;
  float* wsWt = (float*)d_ws;                      // WtT: 256*128*192 floats = 25.2 MB
  float* wsC  = wsWt + (size_t)256*Mm*Nn;          // 256*128 floats
  precompute_kernel<<<256, 512, 0, stream>>>(P, q, A, wsWt, wsC);
  loop_kernel<<<256, 512, LOOP_LDS_FLOATS*4, stream>>>(A, l, u, wsWt, wsC, (float*)d_out);
}